// Round 1
// baseline (1348.700 us; speedup 1.0000x reference)
//
#include <hip/hip_runtime.h>
#include <math.h>

// ---------------------------------------------------------------------------
// MultiResImplicitFeature: out[i] = [sin(arg) (12) | cos(arg) (12) | trilerp
// of 4 grids (4x8)] = 56 fp32 per point.  N = 2,000,000 points.
//
// Strategy round 1:
//   * Transpose grids [C,R,R,R] -> [R,R,R,C] into d_ws so each corner's 8
//     channels are one contiguous 32B block (2 aligned float4 loads) instead
//     of 8 cache lines strided by R^3.  ~5x less gather line traffic.
//   * One thread per point, all stores as aligned float4.
//   * __sincosf (HW v_sin/v_cos) for the 24 transcendentals; threshold 8.4e-2
//     is far above native-sin error.
// ---------------------------------------------------------------------------

__global__ __launch_bounds__(256) void transpose_grid_k(
    const float* __restrict__ in, float* __restrict__ out, int R3)
{
    int v = blockIdx.x * 256 + threadIdx.x;
    if (v >= R3) return;
    float vals[8];
#pragma unroll
    for (int c = 0; c < 8; ++c) vals[c] = in[(size_t)c * R3 + v];
    float4* o = reinterpret_cast<float4*>(out + (size_t)v * 8);
    o[0] = make_float4(vals[0], vals[1], vals[2], vals[3]);
    o[1] = make_float4(vals[4], vals[5], vals[6], vals[7]);
}

template <bool CHLAST>
__device__ __forceinline__ void trilerp8(const float* __restrict__ g, int R,
                                         float px, float py, float pz,
                                         float* __restrict__ orow)
{
    const float rm1 = (float)(R - 1);
    float cx = (px + 1.0f) * 0.5f * rm1;
    float cy = (py + 1.0f) * 0.5f * rm1;
    float cz = (pz + 1.0f) * 0.5f * rm1;
    float fx = floorf(cx), fy = floorf(cy), fz = floorf(cz);
    float wx = cx - fx, wy = cy - fy, wz = cz - fz;
    int x0 = min(max((int)fx, 0), R - 1);
    int y0 = min(max((int)fy, 0), R - 1);
    int z0 = min(max((int)fz, 0), R - 1);
    int x1 = min(x0 + 1, R - 1);
    int y1 = min(y0 + 1, R - 1);
    int z1 = min(z0 + 1, R - 1);

    float wxa[2] = {1.0f - wx, wx};
    float wya[2] = {1.0f - wy, wy};
    float wza[2] = {1.0f - wz, wz};
    int   xi[2]  = {x0, x1};
    int   yi[2]  = {y0, y1};
    int   zi[2]  = {z0, z1};

    float acc[8];
#pragma unroll
    for (int c = 0; c < 8; ++c) acc[c] = 0.0f;

#pragma unroll
    for (int dz = 0; dz < 2; ++dz)
#pragma unroll
        for (int dy = 0; dy < 2; ++dy)
#pragma unroll
            for (int dx = 0; dx < 2; ++dx) {
                float w = wza[dz] * wya[dy] * wxa[dx];
                if (CHLAST) {
                    const float4* p = reinterpret_cast<const float4*>(
                        g + ((((size_t)zi[dz] * R + yi[dy]) * R + xi[dx]) << 3));
                    float4 a = p[0];
                    float4 b = p[1];
                    acc[0] += w * a.x; acc[1] += w * a.y;
                    acc[2] += w * a.z; acc[3] += w * a.w;
                    acc[4] += w * b.x; acc[5] += w * b.y;
                    acc[6] += w * b.z; acc[7] += w * b.w;
                } else {
                    size_t R3   = (size_t)R * R * R;
                    size_t base = ((size_t)zi[dz] * R + yi[dy]) * R + xi[dx];
#pragma unroll
                    for (int c = 0; c < 8; ++c) acc[c] += w * g[c * R3 + base];
                }
            }

    float4* o = reinterpret_cast<float4*>(orow);
    o[0] = make_float4(acc[0], acc[1], acc[2], acc[3]);
    o[1] = make_float4(acc[4], acc[5], acc[6], acc[7]);
}

template <bool CHLAST>
__global__ __launch_bounds__(256) void mrif_kernel(
    const float* __restrict__ x,
    const float* __restrict__ g0, const float* __restrict__ g1,
    const float* __restrict__ g2, const float* __restrict__ g3,
    float* __restrict__ out, int n)
{
    int i = blockIdx.x * 256 + threadIdx.x;
    if (i >= n) return;

    float px = x[3 * i + 0];
    float py = x[3 * i + 1];
    float pz = x[3 * i + 2];

    float* orow = out + (size_t)i * 56;

    // --- sin/cos part: cols [0,12) = sin, [12,24) = cos.
    // arg col l*3+d = (l+1)*(pi/2)*x_d
    const float HPI = 1.57079632679489662f;
    float sv[12], cv[12];
#pragma unroll
    for (int l = 0; l < 4; ++l) {
        float coef = HPI * (float)(l + 1);
        __sincosf(coef * px, &sv[l * 3 + 0], &cv[l * 3 + 0]);
        __sincosf(coef * py, &sv[l * 3 + 1], &cv[l * 3 + 1]);
        __sincosf(coef * pz, &sv[l * 3 + 2], &cv[l * 3 + 2]);
    }
    float4* o4 = reinterpret_cast<float4*>(orow);
    o4[0] = make_float4(sv[0], sv[1], sv[2],  sv[3]);
    o4[1] = make_float4(sv[4], sv[5], sv[6],  sv[7]);
    o4[2] = make_float4(sv[8], sv[9], sv[10], sv[11]);
    o4[3] = make_float4(cv[0], cv[1], cv[2],  cv[3]);
    o4[4] = make_float4(cv[4], cv[5], cv[6],  cv[7]);
    o4[5] = make_float4(cv[8], cv[9], cv[10], cv[11]);

    // --- grid features: cols 24+8g .. (32B chunks, 16B aligned)
    trilerp8<CHLAST>(g0, 16,  px, py, pz, orow + 24);
    trilerp8<CHLAST>(g1, 32,  px, py, pz, orow + 32);
    trilerp8<CHLAST>(g2, 64,  px, py, pz, orow + 40);
    trilerp8<CHLAST>(g3, 128, px, py, pz, orow + 48);
}

extern "C" void kernel_launch(void* const* d_in, const int* in_sizes, int n_in,
                              void* d_out, int out_size, void* d_ws, size_t ws_size,
                              hipStream_t stream)
{
    const float* x = (const float*)d_in[0];
    const float* g[4] = {(const float*)d_in[1], (const float*)d_in[2],
                         (const float*)d_in[3], (const float*)d_in[4]};
    const int R[4] = {16, 32, 64, 128};

    float* out = (float*)d_out;
    const int n = in_sizes[0] / 3;

    size_t voxels[4], offs[4], total = 0;
    for (int k = 0; k < 4; ++k) {
        voxels[k] = (size_t)R[k] * R[k] * R[k];
        offs[k]   = total;
        total    += voxels[k] * 8;
    }

    const int threads = 256;
    const int blocks  = (n + threads - 1) / threads;

    if (ws_size >= total * sizeof(float)) {
        float* wsf = (float*)d_ws;
        for (int k = 0; k < 4; ++k) {
            int r3 = (int)voxels[k];
            transpose_grid_k<<<(r3 + 255) / 256, 256, 0, stream>>>(
                g[k], wsf + offs[k], r3);
        }
        mrif_kernel<true><<<blocks, threads, 0, stream>>>(
            x, wsf + offs[0], wsf + offs[1], wsf + offs[2], wsf + offs[3],
            out, n);
    } else {
        // Fallback: gather straight from the channel-first layout.
        mrif_kernel<false><<<blocks, threads, 0, stream>>>(
            x, g[0], g[1], g[2], g[3], out, n);
    }
}

// Round 2
// 1191.714 us; speedup vs baseline: 1.1317x; 1.1317x over previous
//
#include <hip/hip_runtime.h>
#include <hip/hip_fp16.h>
#include <math.h>

// ---------------------------------------------------------------------------
// MultiResImplicitFeature round 2.
// R1 post-mortem: latency-bound (VALUBusy 2.7%, HBM 42%, VGPR=36 -> tiny
// load batches). Changes:
//   * grids converted to fp16 channel-last in ws: corner = 16B = 1 dwordx4.
//   * explicit batching: issue all 16 gathers for g3+g2, overlap with sincos
//     VALU work, then reduce; then g1+g0 (L2-resident).
//   * full 56-float output buffered in regs, stored once as 14 nontemporal
//     float4 -> no partial-line RMW, no L2 pollution from streaming writes.
// ---------------------------------------------------------------------------

typedef float f32x4 __attribute__((ext_vector_type(4)));

__global__ __launch_bounds__(256) void transpose_grid_h(
    const float* __restrict__ in, __half* __restrict__ out, int R3)
{
    int v = blockIdx.x * 256 + threadIdx.x;
    if (v >= R3) return;
    union { __half h[8]; f32x4 f; } u;
#pragma unroll
    for (int c = 0; c < 8; ++c) u.h[c] = __float2half(in[(size_t)c * R3 + v]);
    *reinterpret_cast<f32x4*>(out + (size_t)v * 8) = u.f;
}

template <int R>
__device__ __forceinline__ void gather8(const __half* __restrict__ g,
                                        float px, float py, float pz,
                                        f32x4 d[8], float w[8])
{
    const float rm1 = (float)(R - 1);
    float cx = (px + 1.0f) * 0.5f * rm1;
    float cy = (py + 1.0f) * 0.5f * rm1;
    float cz = (pz + 1.0f) * 0.5f * rm1;
    float fx = floorf(cx), fy = floorf(cy), fz = floorf(cz);
    float wx = cx - fx, wy = cy - fy, wz = cz - fz;
    int x0 = min(max((int)fx, 0), R - 1);
    int y0 = min(max((int)fy, 0), R - 1);
    int z0 = min(max((int)fz, 0), R - 1);
    int x1 = min(x0 + 1, R - 1);
    int y1 = min(y0 + 1, R - 1);
    int z1 = min(z0 + 1, R - 1);

    int r00 = (z0 * R + y0) * R;
    int r01 = (z0 * R + y1) * R;
    int r10 = (z1 * R + y0) * R;
    int r11 = (z1 * R + y1) * R;

    // corner order: (dz,dy,dx) = 000,001,010,011,100,101,110,111
    int idx[8] = {r00 + x0, r00 + x1, r01 + x0, r01 + x1,
                  r10 + x0, r10 + x1, r11 + x0, r11 + x1};
#pragma unroll
    for (int k = 0; k < 8; ++k)
        d[k] = *reinterpret_cast<const f32x4*>(g + ((size_t)idx[k] << 3));

    float vx = 1.0f - wx, vy = 1.0f - wy, vz = 1.0f - wz;
    w[0] = vz * vy * vx; w[1] = vz * vy * wx;
    w[2] = vz * wy * vx; w[3] = vz * wy * wx;
    w[4] = wz * vy * vx; w[5] = wz * vy * wx;
    w[6] = wz * wy * vx; w[7] = wz * wy * wx;
}

__device__ __forceinline__ void reduce8(const f32x4 d[8], const float w[8],
                                        float* __restrict__ o)
{
    float acc[8];
#pragma unroll
    for (int c = 0; c < 8; ++c) acc[c] = 0.0f;
#pragma unroll
    for (int k = 0; k < 8; ++k) {
        union { f32x4 f; __half2 h2[4]; } u;
        u.f = d[k];
        float wk = w[k];
        float2 p0 = __half22float2(u.h2[0]);
        float2 p1 = __half22float2(u.h2[1]);
        float2 p2 = __half22float2(u.h2[2]);
        float2 p3 = __half22float2(u.h2[3]);
        acc[0] += wk * p0.x; acc[1] += wk * p0.y;
        acc[2] += wk * p1.x; acc[3] += wk * p1.y;
        acc[4] += wk * p2.x; acc[5] += wk * p2.y;
        acc[6] += wk * p3.x; acc[7] += wk * p3.y;
    }
#pragma unroll
    for (int c = 0; c < 8; ++c) o[c] = acc[c];
}

__global__ __launch_bounds__(256) void mrif_h_kernel(
    const float* __restrict__ x,
    const __half* __restrict__ g0, const __half* __restrict__ g1,
    const __half* __restrict__ g2, const __half* __restrict__ g3,
    float* __restrict__ out, int n)
{
    int i = blockIdx.x * 256 + threadIdx.x;
    if (i >= n) return;

    float px = x[3 * i + 0];
    float py = x[3 * i + 1];
    float pz = x[3 * i + 2];

    f32x4 obuf[14];
    float* o = reinterpret_cast<float*>(obuf);

    // ---- issue the two L2-missing gathers first (16 dwordx4 in flight) ----
    f32x4 d3[8]; float w3[8];
    gather8<128>(g3, px, py, pz, d3, w3);
    f32x4 d2[8]; float w2[8];
    gather8<64>(g2, px, py, pz, d2, w2);

    // ---- VALU work overlaps the in-flight gathers ----
    const float HPI = 1.57079632679489662f;
#pragma unroll
    for (int l = 0; l < 4; ++l) {
        float coef = HPI * (float)(l + 1);
        __sincosf(coef * px, &o[l * 3 + 0], &o[12 + l * 3 + 0]);
        __sincosf(coef * py, &o[l * 3 + 1], &o[12 + l * 3 + 1]);
        __sincosf(coef * pz, &o[l * 3 + 2], &o[12 + l * 3 + 2]);
    }

    reduce8(d3, w3, o + 48);
    reduce8(d2, w2, o + 40);

    // ---- small grids: L2/L3-resident, short latency ----
    f32x4 d1[8]; float w1[8];
    gather8<32>(g1, px, py, pz, d1, w1);
    f32x4 d0[8]; float w0[8];
    gather8<16>(g0, px, py, pz, d0, w0);
    reduce8(d1, w1, o + 32);
    reduce8(d0, w0, o + 24);

    // ---- one burst of 14 aligned nontemporal float4 stores ----
    f32x4* dst = reinterpret_cast<f32x4*>(out + (size_t)i * 56);
#pragma unroll
    for (int k = 0; k < 14; ++k)
        __builtin_nontemporal_store(obuf[k], dst + k);
}

// Fallback (ws too small): gather fp32 channel-first directly.
__global__ __launch_bounds__(256) void mrif_fallback_kernel(
    const float* __restrict__ x,
    const float* __restrict__ g0, const float* __restrict__ g1,
    const float* __restrict__ g2, const float* __restrict__ g3,
    float* __restrict__ out, int n)
{
    int i = blockIdx.x * 256 + threadIdx.x;
    if (i >= n) return;
    float px = x[3 * i + 0], py = x[3 * i + 1], pz = x[3 * i + 2];
    float* orow = out + (size_t)i * 56;

    const float HPI = 1.57079632679489662f;
#pragma unroll
    for (int l = 0; l < 4; ++l) {
        float coef = HPI * (float)(l + 1);
        __sincosf(coef * px, &orow[l * 3 + 0], &orow[12 + l * 3 + 0]);
        __sincosf(coef * py, &orow[l * 3 + 1], &orow[12 + l * 3 + 1]);
        __sincosf(coef * pz, &orow[l * 3 + 2], &orow[12 + l * 3 + 2]);
    }
    const float* gs[4] = {g0, g1, g2, g3};
    const int Rs[4] = {16, 32, 64, 128};
    for (int gi = 0; gi < 4; ++gi) {
        const float* g = gs[gi];
        int R = Rs[gi];
        const float rm1 = (float)(R - 1);
        float cx = (px + 1.0f) * 0.5f * rm1;
        float cy = (py + 1.0f) * 0.5f * rm1;
        float cz = (pz + 1.0f) * 0.5f * rm1;
        float fx = floorf(cx), fy = floorf(cy), fz = floorf(cz);
        float wx = cx - fx, wy = cy - fy, wz = cz - fz;
        int x0 = min(max((int)fx, 0), R - 1);
        int y0 = min(max((int)fy, 0), R - 1);
        int z0 = min(max((int)fz, 0), R - 1);
        int x1 = min(x0 + 1, R - 1), y1 = min(y0 + 1, R - 1), z1 = min(z0 + 1, R - 1);
        size_t R3 = (size_t)R * R * R;
        float wxa[2] = {1.0f - wx, wx}, wya[2] = {1.0f - wy, wy}, wza[2] = {1.0f - wz, wz};
        int xi[2] = {x0, x1}, yi[2] = {y0, y1}, zi[2] = {z0, z1};
        float acc[8];
        for (int c = 0; c < 8; ++c) acc[c] = 0.0f;
        for (int dz = 0; dz < 2; ++dz)
            for (int dy = 0; dy < 2; ++dy)
                for (int dx = 0; dx < 2; ++dx) {
                    float w = wza[dz] * wya[dy] * wxa[dx];
                    size_t base = ((size_t)zi[dz] * R + yi[dy]) * R + xi[dx];
                    for (int c = 0; c < 8; ++c) acc[c] += w * g[c * R3 + base];
                }
        for (int c = 0; c < 8; ++c) orow[24 + gi * 8 + c] = acc[c];
    }
}

extern "C" void kernel_launch(void* const* d_in, const int* in_sizes, int n_in,
                              void* d_out, int out_size, void* d_ws, size_t ws_size,
                              hipStream_t stream)
{
    const float* x = (const float*)d_in[0];
    const float* g[4] = {(const float*)d_in[1], (const float*)d_in[2],
                         (const float*)d_in[3], (const float*)d_in[4]};
    const int R[4] = {16, 32, 64, 128};

    float* out = (float*)d_out;
    const int n = in_sizes[0] / 3;

    size_t voxels[4], offs[4], total = 0;
    for (int k = 0; k < 4; ++k) {
        voxels[k] = (size_t)R[k] * R[k] * R[k];
        offs[k]   = total;
        total    += voxels[k] * 8;   // halves
    }

    const int threads = 256;
    const int blocks  = (n + threads - 1) / threads;

    if (ws_size >= total * sizeof(__half)) {
        __half* wsh = (__half*)d_ws;
        for (int k = 0; k < 4; ++k) {
            int r3 = (int)voxels[k];
            transpose_grid_h<<<(r3 + 255) / 256, 256, 0, stream>>>(
                g[k], wsh + offs[k], r3);
        }
        mrif_h_kernel<<<blocks, threads, 0, stream>>>(
            x, wsh + offs[0], wsh + offs[1], wsh + offs[2], wsh + offs[3],
            out, n);
    } else {
        mrif_fallback_kernel<<<blocks, threads, 0, stream>>>(
            x, g[0], g[1], g[2], g[3], out, n);
    }
}